// Round 5
// baseline (37.954 us; speedup 1.0000x reference)
//
#include <hip/hip_runtime.h>
#include <stdint.h>

// Problem constants (match reference setup_inputs)
#define BATCH   8
#define CIMG    3
#define HFULL   512
#define WFULL   512
#define HWFULL  (HFULL * WFULL)          // 262144
#define CFEAT   64
#define HE      128
#define WE      128
#define HWE     (HE * WE)                // 16384
#define NSEG    64
#define NBSEG   (BATCH * NSEG)           // 512
#define WALL_COT 0.5f
#define MIN_FRAC 0.01f

#define NBLK    2048                     // 2048 blocks x 256 threads
#define NREP    8                        // replicated global bin sets (contention /8)

// ws float layout:
// [0 .. NREP*3*512)  replicated bins: per rep { cnt[512] | sum[512] | pos[512] }
// then per-block recovery numerator / denominator (plain stores)
#define WS_BINS_FLOATS (NREP * 3 * NBSEG)
#define WS_BNUM  WS_BINS_FLOATS
#define WS_BDEN  (WS_BINS_FLOATS + NBLK)
#define WS_ZERO_FLOATS WS_BINS_FLOATS

#define KEEPF4(v) asm volatile("" :: "v"((v).x), "v"((v).y), "v"((v).z), "v"((v).w))

typedef uint32_t u32g __attribute__((address_space(1)));
typedef uint32_t u32l __attribute__((address_space(3)));

__global__ __launch_bounds__(256, 2) void confloss_main_kernel(
    const float* __restrict__ outputs, const float* __restrict__ inputs,
    const float* __restrict__ enc1,    const float* __restrict__ dec1,
    const float* __restrict__ masks,   const int* __restrict__ segs,
    float* __restrict__ ws)
{
    const int tid = threadIdx.x;
    const int w   = tid >> 6;            // wave id [0,4)
    const int l   = tid & 63;            // lane id
    const int i   = blockIdx.x * 256 + tid;

    // A-stage buffer: [wave][chunk e0..e3,d0..d3][64 lanes x 4 floats] = 32 KB
    __shared__ float sA[4][8][256];
    __shared__ float s_sumW[4][NSEG];    // per-wave sum-bins (no inter-wave contention)
    __shared__ float s_cnt[NSEG], s_pos[NSEG];
    __shared__ float s_rn[4], s_rd[4];

    s_sumW[w][l] = 0.f;                  // each wave zeroes its own replica
    if (tid < NSEG) { s_cnt[tid] = 0.f; s_pos[tid] = 0.f; }
    __syncthreads();                     // before any cross-wave bin use (no vmem yet)

    // ---- A-task decode: px-group g (4 px), 4-channel slice c ----
    const int g  = i & 32767;            // [0,32768): 8 batches x 4096 groups
    const int c  = i >> 15;              // [0,16): block-uniform
    const int ba = g >> 12;              // batch (block-uniform)
    const int ra = (g & 4095) * 4;       // px offset in 128x128 plane; lane-contig x16B
    const size_t abase = ((size_t)ba * CFEAT + (size_t)c * 4) * HWE + ra;
    const float* ep = enc1 + abase;
    const float* dp = dec1 + abase;

    // ---- issue 8 async global->LDS DMA loads (zero VGPR results, deep vmcnt) ----
#if __has_builtin(__builtin_amdgcn_global_load_lds)
#pragma unroll
    for (int k = 0; k < 4; ++k)
        __builtin_amdgcn_global_load_lds((const u32g*)(ep + (size_t)k * HWE),
                                         (u32l*)(&sA[w][k][0]), 16, 0, 0);
#pragma unroll
    for (int k = 0; k < 4; ++k)
        __builtin_amdgcn_global_load_lds((const u32g*)(dp + (size_t)k * HWE),
                                         (u32l*)(&sA[w][4 + k][0]), 16, 0, 0);
#else
#pragma unroll
    for (int k = 0; k < 4; ++k) {
        *(float4*)&sA[w][k][l * 4]     = *(const float4*)(ep + (size_t)k * HWE);
        *(float4*)&sA[w][4 + k][l * 4] = *(const float4*)(dp + (size_t)k * HWE);
    }
#endif

    // ---- B-task: 4 full-res px, loads into registers, pinned live ----
    const int bb = i >> 16;
    const int rb = (i & 65535) * 4;
    const float* ob = outputs + (size_t)bb * (CIMG * HWFULL) + rb;
    const float* ib = inputs  + (size_t)bb * (CIMG * HWFULL) + rb;
    const float4 mB = *(const float4*)(masks + (size_t)bb * HWFULL + rb);
    const float4 o0 = *(const float4*)(ob);
    const float4 o1 = *(const float4*)(ob + HWFULL);
    const float4 o2 = *(const float4*)(ob + 2 * HWFULL);
    const float4 i0 = *(const float4*)(ib);
    const float4 i1 = *(const float4*)(ib + HWFULL);
    const float4 i2 = *(const float4*)(ib + 2 * HWFULL);

    // seg/mask gather at nearest-neighbor full-res positions (4y, 4x+{0,4,8,12})
    const int ya = ra >> 7, xa = ra & (WE - 1);
    const int fb = ba * HWFULL + (ya * 4) * WFULL + xa * 4;
    const int s0 = segs[fb], s1 = segs[fb + 4], s2 = segs[fb + 8], s3 = segs[fb + 12];
    const bool duty = (c == (g & 15));   // exactly one c-slice counts each px-group
    float mk0 = 1.f, mk1 = 1.f, mk2 = 1.f, mk3 = 1.f;
    if (duty) {
        mk0 = masks[fb];     mk1 = masks[fb + 4];
        mk2 = masks[fb + 8]; mk3 = masks[fb + 12];
    }

    // pin all register loads live so the scheduler can't sink/serialize them,
    // then one wait covering the LDS-DMA queue too
    KEEPF4(mB); KEEPF4(o0); KEEPF4(o1); KEEPF4(o2);
    KEEPF4(i0); KEEPF4(i1); KEEPF4(i2);
    asm volatile("" :: "v"(s0), "v"(s1), "v"(s2), "v"(s3));
    asm volatile("s_waitcnt vmcnt(0)" ::: "memory");

    // ---- B consume: recovery loss partials (registers only) ----
    float num = 0.f, den = 0.f;
    {
        float tgt, dd, mse;
        mse = 0.f;
        tgt = (mB.x >= WALL_COT) ? 0.f : i0.x; dd = o0.x - tgt; mse += dd * dd;
        tgt = (mB.x >= WALL_COT) ? 0.f : i1.x; dd = o1.x - tgt; mse += dd * dd;
        tgt = (mB.x >= WALL_COT) ? 0.f : i2.x; dd = o2.x - tgt; mse += dd * dd;
        if (mB.x > 0.f) { num += mse; den += 1.f; }
        mse = 0.f;
        tgt = (mB.y >= WALL_COT) ? 0.f : i0.y; dd = o0.y - tgt; mse += dd * dd;
        tgt = (mB.y >= WALL_COT) ? 0.f : i1.y; dd = o1.y - tgt; mse += dd * dd;
        tgt = (mB.y >= WALL_COT) ? 0.f : i2.y; dd = o2.y - tgt; mse += dd * dd;
        if (mB.y > 0.f) { num += mse; den += 1.f; }
        mse = 0.f;
        tgt = (mB.z >= WALL_COT) ? 0.f : i0.z; dd = o0.z - tgt; mse += dd * dd;
        tgt = (mB.z >= WALL_COT) ? 0.f : i1.z; dd = o1.z - tgt; mse += dd * dd;
        tgt = (mB.z >= WALL_COT) ? 0.f : i2.z; dd = o2.z - tgt; mse += dd * dd;
        if (mB.z > 0.f) { num += mse; den += 1.f; }
        mse = 0.f;
        tgt = (mB.w >= WALL_COT) ? 0.f : i0.w; dd = o0.w - tgt; mse += dd * dd;
        tgt = (mB.w >= WALL_COT) ? 0.f : i1.w; dd = o1.w - tgt; mse += dd * dd;
        tgt = (mB.w >= WALL_COT) ? 0.f : i2.w; dd = o2.w - tgt; mse += dd * dd;
        if (mB.w > 0.f) { num += mse; den += 1.f; }
    }

    // ---- A consume: read back own lanes' staged data from LDS ----
    {
        const float4 E0 = *(const float4*)&sA[w][0][l * 4];
        const float4 E1 = *(const float4*)&sA[w][1][l * 4];
        const float4 E2 = *(const float4*)&sA[w][2][l * 4];
        const float4 E3 = *(const float4*)&sA[w][3][l * 4];
        const float4 D0 = *(const float4*)&sA[w][4][l * 4];
        const float4 D1 = *(const float4*)&sA[w][5][l * 4];
        const float4 D2 = *(const float4*)&sA[w][6][l * 4];
        const float4 D3 = *(const float4*)&sA[w][7][l * 4];

        float t0, t1, t2, t3;
        t0 = E0.x - D0.x; t1 = E1.x - D1.x; t2 = E2.x - D2.x; t3 = E3.x - D3.x;
        const float p0 = (t0*t0 + t1*t1 + t2*t2 + t3*t3) * (1.0f / (float)CFEAT);
        t0 = E0.y - D0.y; t1 = E1.y - D1.y; t2 = E2.y - D2.y; t3 = E3.y - D3.y;
        const float p1 = (t0*t0 + t1*t1 + t2*t2 + t3*t3) * (1.0f / (float)CFEAT);
        t0 = E0.z - D0.z; t1 = E1.z - D1.z; t2 = E2.z - D2.z; t3 = E3.z - D3.z;
        const float p2 = (t0*t0 + t1*t1 + t2*t2 + t3*t3) * (1.0f / (float)CFEAT);
        t0 = E0.w - D0.w; t1 = E1.w - D1.w; t2 = E2.w - D2.w; t3 = E3.w - D3.w;
        const float p3 = (t0*t0 + t1*t1 + t2*t2 + t3*t3) * (1.0f / (float)CFEAT);

        atomicAdd(&s_sumW[w][s0], p0);
        atomicAdd(&s_sumW[w][s1], p1);
        atomicAdd(&s_sumW[w][s2], p2);
        atomicAdd(&s_sumW[w][s3], p3);
        if (duty) {
            atomicAdd(&s_cnt[s0], 1.f); if (mk0 > 0.f && mk0 < WALL_COT) atomicAdd(&s_pos[s0], 1.f);
            atomicAdd(&s_cnt[s1], 1.f); if (mk1 > 0.f && mk1 < WALL_COT) atomicAdd(&s_pos[s1], 1.f);
            atomicAdd(&s_cnt[s2], 1.f); if (mk2 > 0.f && mk2 < WALL_COT) atomicAdd(&s_pos[s2], 1.f);
            atomicAdd(&s_cnt[s3], 1.f); if (mk3 > 0.f && mk3 < WALL_COT) atomicAdd(&s_pos[s3], 1.f);
        }
    }

    // ---- B wave reduce -> per-block partial ----
#pragma unroll
    for (int off = 32; off >= 1; off >>= 1) {
        num += __shfl_down(num, off);
        den += __shfl_down(den, off);
    }
    if (l == 0) { s_rn[w] = num; s_rd[w] = den; }
    __syncthreads();

    if (tid == 0) {
        ws[WS_BNUM + blockIdx.x] = s_rn[0] + s_rn[1] + s_rn[2] + s_rn[3];
        ws[WS_BDEN + blockIdx.x] = s_rd[0] + s_rd[1] + s_rd[2] + s_rd[3];
    }
    if (tid < NSEG) {
        const int rep  = blockIdx.x & (NREP - 1);
        float* bins = ws + rep * (3 * NBSEG);
        const int gb = ba * NSEG + tid;
        const float sv = s_sumW[0][tid] + s_sumW[1][tid] + s_sumW[2][tid] + s_sumW[3][tid];
        if (sv != 0.f) atomicAdd(&bins[NBSEG + gb], sv);
        const float cv = s_cnt[tid];
        if (cv != 0.f) atomicAdd(&bins[gb], cv);
        const float pv = s_pos[tid];
        if (pv != 0.f) atomicAdd(&bins[2 * NBSEG + gb], pv);
    }
}

__global__ __launch_bounds__(512) void confloss_finalize_kernel(
    const float* __restrict__ ws, float* __restrict__ out)
{
    const int t = threadIdx.x;   // one per (b,seg); also 4 B-partials each
    float rn = 0.f, rd = 0.f;
#pragma unroll
    for (int k = 0; k < NBLK / 512; ++k) {
        rn += ws[WS_BNUM + t + k * 512];
        rd += ws[WS_BDEN + t + k * 512];
    }
    float cnt = 0.f, sum = 0.f, pos = 0.f;
#pragma unroll
    for (int rep = 0; rep < NREP; ++rep) {
        const float* bins = ws + rep * (3 * NBSEG);
        cnt += bins[t];
        sum += bins[NBSEG + t];
        pos += bins[2 * NBSEG + t];
    }
    const float safe = fmaxf(cnt, 1.0f);
    const float mean = sum / safe;
    const bool valid = (cnt / (float)HWE) >= MIN_FRAC;
    const bool posf  = (pos / safe) > MIN_FRAC;
    float sel = (valid && posf) ? 1.0f : 0.0f;
    float val = mean * sel;

#pragma unroll
    for (int off = 32; off >= 1; off >>= 1) {
        val += __shfl_down(val, off);
        sel += __shfl_down(sel, off);
        rn  += __shfl_down(rn,  off);
        rd  += __shfl_down(rd,  off);
    }
    __shared__ float sv[8], ss[8], sn[8], sd[8];
    const int wid = t >> 6;
    if ((t & 63) == 0) { sv[wid] = val; ss[wid] = sel; sn[wid] = rn; sd[wid] = rd; }
    __syncthreads();
    if (t == 0) {
        float tv = 0.f, ts = 0.f, tn = 0.f, td = 0.f;
#pragma unroll
        for (int w = 0; w < 8; ++w) { tv += sv[w]; ts += ss[w]; tn += sn[w]; td += sd[w]; }
        const float flat_pos_mean = tv / fmaxf(ts, 1.0f);
        const float loss_recov = tn / fmaxf(td, 1.0f);
        out[0] = loss_recov + flat_pos_mean;
    }
}

extern "C" void kernel_launch(void* const* d_in, const int* in_sizes, int n_in,
                              void* d_out, int out_size, void* d_ws, size_t ws_size,
                              hipStream_t stream) {
    const float* outputs = (const float*)d_in[0];
    const float* inputs  = (const float*)d_in[1];
    const float* enc1    = (const float*)d_in[2];
    const float* dec1    = (const float*)d_in[3];
    const float* masks   = (const float*)d_in[4];
    const int*   segs    = (const int*)d_in[5];
    float* ws  = (float*)d_ws;
    float* out = (float*)d_out;

    // atomic bins must be zeroed every call (harness poisons ws once, never re-zeros)
    hipMemsetAsync(ws, 0, WS_ZERO_FLOATS * sizeof(float), stream);

    confloss_main_kernel<<<NBLK, 256, 0, stream>>>(
        outputs, inputs, enc1, dec1, masks, segs, ws);
    confloss_finalize_kernel<<<1, 512, 0, stream>>>(ws, out);
}

// Round 6
// 37.300 us; speedup vs baseline: 1.0175x; 1.0175x over previous
//
#include <hip/hip_runtime.h>
#include <stdint.h>

// Problem constants (match reference setup_inputs)
#define BATCH   8
#define CIMG    3
#define HFULL   512
#define WFULL   512
#define HWFULL  (HFULL * WFULL)          // 262144
#define CFEAT   64
#define HE      128
#define WE      128
#define HWE     (HE * WE)                // 16384
#define NSEG    64
#define NBSEG   (BATCH * NSEG)           // 512
#define WALL_COT 0.5f
#define MIN_FRAC 0.01f

#define NBLK    2048                     // main: 2048 blocks x 256 threads
#define NREP    8                        // replicated global bin sets

// ws float layout:
// [0 .. 12288)        replicated bins: per rep { cnt[512] | sum[512] | pos[512] }
// [12288 .. 14336)    per-block recovery numerator   (plain store)
// [14336 .. 16384)    per-block recovery denominator (plain store)
// [16384 .. 147456)   packed seg_ds[131072] (int: seg | pos_flag<<8), written by pre-kernel
#define WS_BINS_FLOATS (NREP * 3 * NBSEG)            // 12288
#define WS_BNUM  WS_BINS_FLOATS
#define WS_BDEN  (WS_BNUM + NBLK)
#define WS_SEGDS (WS_BDEN + NBLK)                    // 16384 (as int*)
#define WS_ZERO_FLOATS WS_BINS_FLOATS

#define KEEPF4(v) asm volatile("" :: "v"((v).x), "v"((v).y), "v"((v).z), "v"((v).w))
#define KEEPI4(v) asm volatile("" :: "v"((v).x), "v"((v).y), "v"((v).z), "v"((v).w))

// Pre-pass: per feature pixel, gather seg + mask at the nearest-neighbor full-res
// position ONCE (the only scattered reads in the whole pipeline), pack into one
// int. Also zeroes the atomic bins (replaces the memset launch).
__global__ __launch_bounds__(256) void confloss_pre_kernel(
    const float* __restrict__ masks, const int* __restrict__ segs,
    float* __restrict__ ws)
{
    const int p = blockIdx.x * 256 + threadIdx.x;   // [0, 131072)
    const int b = p >> 14;
    const int r = p & (HWE - 1);
    const int y = r >> 7, x = r & (WE - 1);
    const int src = b * HWFULL + (y * 4) * WFULL + x * 4;
    const int   seg = segs[src];
    const float mk  = masks[src];
    const int packed = seg | ((mk > 0.f && mk < WALL_COT) ? 256 : 0);
    ((int*)(ws + WS_SEGDS))[p] = packed;
    if (p < WS_ZERO_FLOATS) ws[p] = 0.f;
}

__global__ __launch_bounds__(256, 2) void confloss_main_kernel(
    const float* __restrict__ outputs, const float* __restrict__ inputs,
    const float* __restrict__ enc1,    const float* __restrict__ dec1,
    const float* __restrict__ masks,   const int* __restrict__ segs,
    float* __restrict__ ws)
{
    const int tid = threadIdx.x;
    const int w   = tid >> 6;            // wave id [0,4)
    const int l   = tid & 63;            // lane id
    const int i   = blockIdx.x * 256 + tid;

    __shared__ float s_sumW[4][NSEG];    // per-wave sum bins (no inter-wave contention)
    __shared__ float s_cnt[NSEG], s_pos[NSEG];
    __shared__ float s_rn[4], s_rd[4];
    s_sumW[w][l] = 0.f;
    if (tid < NSEG) { s_cnt[tid] = 0.f; s_pos[tid] = 0.f; }
    __syncthreads();

    // ---- A-task decode: px-group g (4 px), 4-channel slice c ----
    const int g  = i & 32767;            // [0,32768): 8 batches x 4096 groups
    const int c  = i >> 15;              // [0,16): block-uniform
    const int ba = g >> 12;              // batch (block-uniform)
    const int ra = (g & 4095) * 4;       // px offset in 128x128 plane
    const size_t abase = ((size_t)ba * CFEAT + (size_t)c * 4) * HWE + ra;
    const float* ep = enc1 + abase;
    const float* dp = dec1 + abase;

    // ---- B-task decode: 4 full-res px ----
    const int bb = i >> 16;
    const int rb = (i & 65535) * 4;
    const float* ob = outputs + (size_t)bb * (CIMG * HWFULL) + rb;
    const float* ib = inputs  + (size_t)bb * (CIMG * HWFULL) + rb;

    // ---- issue ALL loads upfront: 16 dense 16B loads, zero scatter ----
    const float4 e0 = *(const float4*)(ep);
    const float4 e1 = *(const float4*)(ep + HWE);
    const float4 e2 = *(const float4*)(ep + 2 * HWE);
    const float4 e3 = *(const float4*)(ep + 3 * HWE);
    const float4 d0 = *(const float4*)(dp);
    const float4 d1 = *(const float4*)(dp + HWE);
    const float4 d2 = *(const float4*)(dp + 2 * HWE);
    const float4 d3 = *(const float4*)(dp + 3 * HWE);
    const float4 mB = *(const float4*)(masks + (size_t)bb * HWFULL + rb);
    const float4 o0 = *(const float4*)(ob);
    const float4 o1 = *(const float4*)(ob + HWFULL);
    const float4 o2 = *(const float4*)(ob + 2 * HWFULL);
    const float4 i0 = *(const float4*)(ib);
    const float4 i1 = *(const float4*)(ib + HWFULL);
    const float4 i2 = *(const float4*)(ib + 2 * HWFULL);
    const int4 pk = *(const int4*)(((const int*)(ws + WS_SEGDS)) + 4 * g);

    // pin everything live -> compiler cannot sink/serialize; one drain
    KEEPF4(e0); KEEPF4(e1); KEEPF4(e2); KEEPF4(e3);
    KEEPF4(d0); KEEPF4(d1); KEEPF4(d2); KEEPF4(d3);
    KEEPF4(mB); KEEPF4(o0); KEEPF4(o1); KEEPF4(o2);
    KEEPF4(i0); KEEPF4(i1); KEEPF4(i2); KEEPI4(pk);
    asm volatile("s_waitcnt vmcnt(0)" ::: "memory");

    // ---- B consume: recovery loss partials ----
    float num = 0.f, den = 0.f;
    {
        float tgt, dd, mse;
        mse = 0.f;
        tgt = (mB.x >= WALL_COT) ? 0.f : i0.x; dd = o0.x - tgt; mse += dd * dd;
        tgt = (mB.x >= WALL_COT) ? 0.f : i1.x; dd = o1.x - tgt; mse += dd * dd;
        tgt = (mB.x >= WALL_COT) ? 0.f : i2.x; dd = o2.x - tgt; mse += dd * dd;
        if (mB.x > 0.f) { num += mse; den += 1.f; }
        mse = 0.f;
        tgt = (mB.y >= WALL_COT) ? 0.f : i0.y; dd = o0.y - tgt; mse += dd * dd;
        tgt = (mB.y >= WALL_COT) ? 0.f : i1.y; dd = o1.y - tgt; mse += dd * dd;
        tgt = (mB.y >= WALL_COT) ? 0.f : i2.y; dd = o2.y - tgt; mse += dd * dd;
        if (mB.y > 0.f) { num += mse; den += 1.f; }
        mse = 0.f;
        tgt = (mB.z >= WALL_COT) ? 0.f : i0.z; dd = o0.z - tgt; mse += dd * dd;
        tgt = (mB.z >= WALL_COT) ? 0.f : i1.z; dd = o1.z - tgt; mse += dd * dd;
        tgt = (mB.z >= WALL_COT) ? 0.f : i2.z; dd = o2.z - tgt; mse += dd * dd;
        if (mB.z > 0.f) { num += mse; den += 1.f; }
        mse = 0.f;
        tgt = (mB.w >= WALL_COT) ? 0.f : i0.w; dd = o0.w - tgt; mse += dd * dd;
        tgt = (mB.w >= WALL_COT) ? 0.f : i1.w; dd = o1.w - tgt; mse += dd * dd;
        tgt = (mB.w >= WALL_COT) ? 0.f : i2.w; dd = o2.w - tgt; mse += dd * dd;
        if (mB.w > 0.f) { num += mse; den += 1.f; }
    }

    // ---- A consume: per-px 4-channel error partials, binned via packed seg ----
    {
        const int s0 = pk.x & 255, s1 = pk.y & 255, s2 = pk.z & 255, s3 = pk.w & 255;
        float t0, t1, t2, t3;
        t0 = e0.x - d0.x; t1 = e1.x - d1.x; t2 = e2.x - d2.x; t3 = e3.x - d3.x;
        const float p0 = (t0*t0 + t1*t1 + t2*t2 + t3*t3) * (1.0f / (float)CFEAT);
        t0 = e0.y - d0.y; t1 = e1.y - d1.y; t2 = e2.y - d2.y; t3 = e3.y - d3.y;
        const float p1 = (t0*t0 + t1*t1 + t2*t2 + t3*t3) * (1.0f / (float)CFEAT);
        t0 = e0.z - d0.z; t1 = e1.z - d1.z; t2 = e2.z - d2.z; t3 = e3.z - d3.z;
        const float p2 = (t0*t0 + t1*t1 + t2*t2 + t3*t3) * (1.0f / (float)CFEAT);
        t0 = e0.w - d0.w; t1 = e1.w - d1.w; t2 = e2.w - d2.w; t3 = e3.w - d3.w;
        const float p3 = (t0*t0 + t1*t1 + t2*t2 + t3*t3) * (1.0f / (float)CFEAT);

        atomicAdd(&s_sumW[w][s0], p0);
        atomicAdd(&s_sumW[w][s1], p1);
        atomicAdd(&s_sumW[w][s2], p2);
        atomicAdd(&s_sumW[w][s3], p3);
        if (c == (g & 15)) {             // exactly one c-slice counts each px-group
            atomicAdd(&s_cnt[s0], 1.f); if (pk.x & 256) atomicAdd(&s_pos[s0], 1.f);
            atomicAdd(&s_cnt[s1], 1.f); if (pk.y & 256) atomicAdd(&s_pos[s1], 1.f);
            atomicAdd(&s_cnt[s2], 1.f); if (pk.z & 256) atomicAdd(&s_pos[s2], 1.f);
            atomicAdd(&s_cnt[s3], 1.f); if (pk.w & 256) atomicAdd(&s_pos[s3], 1.f);
        }
    }

    // ---- B wave reduce -> per-block partial ----
#pragma unroll
    for (int off = 32; off >= 1; off >>= 1) {
        num += __shfl_down(num, off);
        den += __shfl_down(den, off);
    }
    if (l == 0) { s_rn[w] = num; s_rd[w] = den; }
    __syncthreads();

    if (tid == 0) {
        ws[WS_BNUM + blockIdx.x] = s_rn[0] + s_rn[1] + s_rn[2] + s_rn[3];
        ws[WS_BDEN + blockIdx.x] = s_rd[0] + s_rd[1] + s_rd[2] + s_rd[3];
    }
    if (tid < NSEG) {
        const int rep = blockIdx.x & (NREP - 1);
        float* bins = ws + rep * (3 * NBSEG);
        const int gb = ba * NSEG + tid;
        const float sv = s_sumW[0][tid] + s_sumW[1][tid] + s_sumW[2][tid] + s_sumW[3][tid];
        if (sv != 0.f) atomicAdd(&bins[NBSEG + gb], sv);
        const float cv = s_cnt[tid];
        if (cv != 0.f) atomicAdd(&bins[gb], cv);
        const float pv = s_pos[tid];
        if (pv != 0.f) atomicAdd(&bins[2 * NBSEG + gb], pv);
    }
}

__global__ __launch_bounds__(512) void confloss_finalize_kernel(
    const float* __restrict__ ws, float* __restrict__ out)
{
    const int t = threadIdx.x;   // one per (b,seg); also 4 B-partials each
    float rn = 0.f, rd = 0.f;
#pragma unroll
    for (int k = 0; k < NBLK / 512; ++k) {
        rn += ws[WS_BNUM + t + k * 512];
        rd += ws[WS_BDEN + t + k * 512];
    }
    float cnt = 0.f, sum = 0.f, pos = 0.f;
#pragma unroll
    for (int rep = 0; rep < NREP; ++rep) {
        const float* bins = ws + rep * (3 * NBSEG);
        cnt += bins[t];
        sum += bins[NBSEG + t];
        pos += bins[2 * NBSEG + t];
    }
    const float safe = fmaxf(cnt, 1.0f);
    const float mean = sum / safe;
    const bool valid = (cnt / (float)HWE) >= MIN_FRAC;
    const bool posf  = (pos / safe) > MIN_FRAC;
    float sel = (valid && posf) ? 1.0f : 0.0f;
    float val = mean * sel;

#pragma unroll
    for (int off = 32; off >= 1; off >>= 1) {
        val += __shfl_down(val, off);
        sel += __shfl_down(sel, off);
        rn  += __shfl_down(rn,  off);
        rd  += __shfl_down(rd,  off);
    }
    __shared__ float sv[8], ss[8], sn[8], sd[8];
    const int wid = t >> 6;
    if ((t & 63) == 0) { sv[wid] = val; ss[wid] = sel; sn[wid] = rn; sd[wid] = rd; }
    __syncthreads();
    if (t == 0) {
        float tv = 0.f, ts = 0.f, tn = 0.f, td = 0.f;
#pragma unroll
        for (int w = 0; w < 8; ++w) { tv += sv[w]; ts += ss[w]; tn += sn[w]; td += sd[w]; }
        const float flat_pos_mean = tv / fmaxf(ts, 1.0f);
        const float loss_recov = tn / fmaxf(td, 1.0f);
        out[0] = loss_recov + flat_pos_mean;
    }
}

extern "C" void kernel_launch(void* const* d_in, const int* in_sizes, int n_in,
                              void* d_out, int out_size, void* d_ws, size_t ws_size,
                              hipStream_t stream) {
    const float* outputs = (const float*)d_in[0];
    const float* inputs  = (const float*)d_in[1];
    const float* enc1    = (const float*)d_in[2];
    const float* dec1    = (const float*)d_in[3];
    const float* masks   = (const float*)d_in[4];
    const int*   segs    = (const int*)d_in[5];
    float* ws  = (float*)d_ws;
    float* out = (float*)d_out;

    // pre-pass: pack seg+pos per feature px (coalesced for main), zero atomic bins
    confloss_pre_kernel<<<(BATCH * HWE) / 256, 256, 0, stream>>>(masks, segs, ws);
    confloss_main_kernel<<<NBLK, 256, 0, stream>>>(
        outputs, inputs, enc1, dec1, masks, segs, ws);
    confloss_finalize_kernel<<<1, 512, 0, stream>>>(ws, out);
}